// Round 10
// baseline (214.048 us; speedup 1.0000x reference)
//
#include <hip/hip_runtime.h>
#include <math.h>

typedef unsigned short u16;
typedef unsigned int u32;
typedef __attribute__((ext_vector_type(8))) short bf16x8_t;
typedef __attribute__((ext_vector_type(4))) float f32x4_t;

#define S_LEN  2048
#define NH     16
#define DK     64
#define DMODEL 1024
#define MROWS  4096   // B*S
#define LOG2E  1.44269504088896f

__device__ inline u16 f2b(float f) {
  union { float f; u32 u; } c; c.f = f;
  u32 u = c.u;
  return (u16)((u + 0x7fffu + ((u >> 16) & 1u)) >> 16);  // RNE bf16
}

__device__ __forceinline__ float fexp2(float x) {
#if __has_builtin(__builtin_amdgcn_exp2f)
  return __builtin_amdgcn_exp2f(x);
#else
  return exp2f(x);
#endif
}

// ---------------- fused prep: cast x, transpose+cast 4 weights, bias table ----------------
__global__ void prep_kernel(const float* __restrict__ x,
                            const float* __restrict__ Wq, const float* __restrict__ Wk,
                            const float* __restrict__ Wv, const float* __restrict__ Wo,
                            const float* __restrict__ rel,
                            u16* __restrict__ xb, u16* __restrict__ Wall,
                            u16* __restrict__ Wto, float* __restrict__ btab) {
  __shared__ float tile[32][33];
  const int bid = blockIdx.x, t = threadIdx.x;
  if (bid < 4096) {
    int i = (bid * 256 + t) * 4;
    float4 v = *(const float4*)(x + i);
    ushort4 o;
    o.x = f2b(v.x); o.y = f2b(v.y); o.z = f2b(v.z); o.w = f2b(v.w);
    *(ushort4*)(xb + i) = o;
  } else if (bid < 8192) {
    int bid2 = bid - 4096;
    int z = bid2 >> 10, rem = bid2 & 1023;
    const float* W; u16* Wt;
    switch (z) {
      case 0: W = Wq; Wt = Wall; break;
      case 1: W = Wk; Wt = Wall + (size_t)DMODEL * DMODEL; break;
      case 2: W = Wv; Wt = Wall + (size_t)2 * DMODEL * DMODEL; break;
      default: W = Wo; Wt = Wto; break;
    }
    int bc = (rem & 31) * 32, br = (rem >> 5) * 32;
    int tx = t & 31, ty = t >> 5;
    #pragma unroll
    for (int yy = 0; yy < 32; yy += 8)
      tile[ty + yy][tx] = W[(size_t)(br + ty + yy) * DMODEL + bc + tx];
    __syncthreads();
    #pragma unroll
    for (int yy = 0; yy < 32; yy += 8)
      Wt[(size_t)(bc + ty + yy) * DMODEL + br + tx] = f2b(tile[tx][ty + yy]);
  } else {
    // bias table: btab[h][delta+2047] = (bias(h,delta) - 16) * log2(e)   [exp2-domain]
    int idx = (bid - 8192) * 256 + t;
    if (idx < NH * 4095) {
      int h = idx / 4095;
      int dpos = idx - h * 4095;
      int delta = dpos - 2047;               // j - i; reference n = i - j
      int ret = (delta > 0) ? 16 : 0;
      int n = delta < 0 ? -delta : delta;
      int bucket;
      if (n < 8) {
        bucket = ret + n;
      } else {
        float vf = logf((float)n * 0.125f) / 2.7725887222397811f * 8.0f;
        int vil = 8 + (int)vf;
        bucket = ret + (vil < 15 ? vil : 15);
      }
      btab[idx] = (rel[bucket * NH + h] - 16.0f) * LOG2E;
    }
  }
}

// ---------------- 128x128 bf16 MFMA GEMM, manual staging + SW pipeline (R5-proven core) ----------------
#define GSTR 56   // u16 LDS row stride (112 B): 16B-aligned, 2-way bank aliasing (free per m136)
__global__ __launch_bounds__(256) void gemm128_kernel(const u16* __restrict__ A,
                                                      const u16* __restrict__ Bt,
                                                      float* __restrict__ C,
                                                      u16* __restrict__ q16,
                                                      u16* __restrict__ k16,
                                                      u16* __restrict__ vt16,
                                                      int mode) {
  __shared__ __align__(16) u16 As[128 * GSTR];  // 14336 B
  __shared__ __align__(16) u16 Bs[128 * GSTR];
  const int t = threadIdx.x, w = t >> 6, l = t & 63;
  const int c = l & 15, quad = l >> 4;
  const int m0 = blockIdx.x * 128, n0 = blockIdx.y * 128;
  const int wm = (w & 1) * 64, wn = (w >> 1) * 64;

  const int sr = t >> 2;
  const int k8 = (t & 3) * 8;
  const u16* Ag0 = A  + (size_t)(m0 + sr) * DMODEL + k8;
  const u16* Ag1 = Ag0 + (size_t)64 * DMODEL;
  const u16* Bg0 = Bt + (size_t)(n0 + sr) * DMODEL + k8;
  const u16* Bg1 = Bg0 + (size_t)64 * DMODEL;
  u16* Al0 = As + sr * GSTR + k8;
  u16* Al1 = Al0 + 64 * GSTR;
  u16* Bl0 = Bs + sr * GSTR + k8;
  u16* Bl1 = Bl0 + 64 * GSTR;

  uint4 a0 = *(const uint4*)Ag0, a1 = *(const uint4*)Ag1;
  uint4 b0 = *(const uint4*)Bg0, b1 = *(const uint4*)Bg1;

  f32x4_t acc[16] = {};
  for (int k0 = 0; k0 < DMODEL; k0 += 32) {
    __syncthreads();
    *(uint4*)Al0 = a0; *(uint4*)Al1 = a1;
    *(uint4*)Bl0 = b0; *(uint4*)Bl1 = b1;
    __syncthreads();
    if (k0 + 32 < DMODEL) {
      a0 = *(const uint4*)(Ag0 + k0 + 32);
      a1 = *(const uint4*)(Ag1 + k0 + 32);
      b0 = *(const uint4*)(Bg0 + k0 + 32);
      b1 = *(const uint4*)(Bg1 + k0 + 32);
    }
    bf16x8_t af[4], bfr[4];
    #pragma unroll
    for (int i = 0; i < 4; ++i) {
      af[i]  = *(const bf16x8_t*)(As + (wm + i * 16 + c) * GSTR + quad * 8);
      bfr[i] = *(const bf16x8_t*)(Bs + (wn + i * 16 + c) * GSTR + quad * 8);
    }
    #pragma unroll
    for (int mt = 0; mt < 4; ++mt)
      #pragma unroll
      for (int nt = 0; nt < 4; ++nt)
        acc[mt * 4 + nt] = __builtin_amdgcn_mfma_f32_16x16x32_bf16(af[mt], bfr[nt], acc[mt * 4 + nt], 0, 0, 0);
  }

  const int whichblk = n0 >> 10;
  if (mode == 0) {
    #pragma unroll
    for (int mt = 0; mt < 4; ++mt) {
      int grow0 = m0 + wm + mt * 16 + quad * 4;
      #pragma unroll
      for (int nt = 0; nt < 4; ++nt) {
        int gcol = n0 + wn + nt * 16 + c;
        #pragma unroll
        for (int r = 0; r < 4; ++r)
          C[(size_t)(grow0 + r) * DMODEL + gcol] = acc[mt * 4 + nt][r];
      }
    }
  } else if (whichblk == 2) {
    #pragma unroll
    for (int mt = 0; mt < 4; ++mt) {
      int grow0 = m0 + wm + mt * 16 + quad * 4;
      int b = grow0 >> 11, s0 = grow0 & 2047;
      #pragma unroll
      for (int nt = 0; nt < 4; ++nt) {
        int cc = (n0 + wn + nt * 16 + c) & 1023;
        int hh = cc >> 6, dk = cc & 63;
        f32x4_t v4 = acc[mt * 4 + nt];
        ushort4 o;
        o.x = f2b(v4[0]); o.y = f2b(v4[1]); o.z = f2b(v4[2]); o.w = f2b(v4[3]);
        *(ushort4*)(vt16 + (((size_t)(b * NH + hh)) * DK + dk) * S_LEN + s0) = o;
      }
    }
  } else {
    u16* tb = (w & 1) ? Bs : As;
    const int base_mw = m0 + wm;
    const int bb = base_mw >> 11, s0g = base_mw & 2047;
    const int cc = (n0 + wn) & 1023;
    const int hh = cc >> 6;
    u16* qk = (whichblk == 0 ? q16 : k16) + (((size_t)(bb * NH + hh)) * S_LEN + s0g) * DK;
    __syncthreads();
    #pragma unroll
    for (int round = 0; round < 2; ++round) {
      if ((w >> 1) == round) {
        #pragma unroll
        for (int mt = 0; mt < 4; ++mt)
          #pragma unroll
          for (int nt = 0; nt < 4; ++nt)
            #pragma unroll
            for (int r = 0; r < 4; ++r)
              tb[(mt * 16 + quad * 4 + r) * 72 + nt * 16 + c] = f2b(acc[mt * 4 + nt][r]);
        #pragma unroll
        for (int i = 0; i < 8; ++i) {
          int lrow = i * 8 + (l >> 3);
          int chk = l & 7;
          uint4 vv = *(const uint4*)(tb + lrow * 72 + chk * 8);
          *(uint4*)(qk + (size_t)lrow * DK + chk * 8) = vv;
        }
      }
      __syncthreads();
    }
  }
}

// ---------------- MFMA flash attention v6: transposed scores (S^T = K·Q^T), packed P writes ----------------
// q,k: bf16 [bh][s][64]; vt: bf16 [bh][64][s]; ctx out: bf16 [b][s][1024]
// S^T C-layout gives each lane 4 values at fixed q (= lane&15), consecutive k -> P row-contiguous:
// P write = 4x ds_write_b64 (packed) instead of 16x ds_write_b16; l-sum = 1 scalar/q-group.
#define ASTR 72   // u16 row stride (144 B): 16B-aligned, 2-way-max bank aliasing
__global__ __launch_bounds__(256) void attn_mfma_kernel(const u16* __restrict__ q,
                                                        const u16* __restrict__ k,
                                                        const u16* __restrict__ vt,
                                                        const float* __restrict__ btab,
                                                        u16* __restrict__ ctx) {
  __shared__ __align__(16) u16 Ks[64 * ASTR];
  __shared__ __align__(16) u16 Vts[64 * ASTR];
  __shared__ __align__(16) u16 Ps[4][16 * ASTR];  // per-wave 16-row P buffer (row = q)
  __shared__ float band[192];                     // exp2-domain bias band
  __shared__ float l_lds[4][32];                  // per-wave l[q] transpose buffer

  const int t = threadIdx.x;
  const int w = t >> 6, l = t & 63;
  const int c = l & 15, quad = l >> 4;
  const int bh = blockIdx.y;
  const int h = bh & (NH - 1), b = bh >> 4;
  const int q0 = blockIdx.x * 128;

  const u16* qb = q + (size_t)bh * S_LEN * DK;
  const u16* kb = k + (size_t)bh * S_LEN * DK;
  const u16* vb = vt + (size_t)bh * DK * S_LEN;
  // band[d] = btp[kt + d]; d = 127 + klocal - qlocal, klocal in [0,64), qlocal in [0,128)
  const float* btp = btab + h * 4095 + (2047 - 127 - q0);

  // Q fragments (rows q0 + w*32 + qg*16 + c) — used as the B operand of K·Q^T
  bf16x8_t qfrag[2][2];
  #pragma unroll
  for (int qg = 0; qg < 2; ++qg) {
    const u16* qp = qb + (size_t)(q0 + w * 32 + qg * 16 + c) * DK + quad * 8;
    qfrag[qg][0] = *(const bf16x8_t*)(qp);
    qfrag[qg][1] = *(const bf16x8_t*)(qp + 32);
  }

  float lp[2] = {0.f, 0.f};   // row sum for q = c (this lane's query), per q-group
  f32x4_t O[2][4] = {};

  // staging (FULL coverage): rows srow, srow+32; 256 thr x 2 x 8 u16 = full 64x64 tile each
  const int srow = t >> 3;
  const int sc8 = (t & 7) * 8;
  const u16* kg0 = kb + (size_t)srow * DK + sc8;
  const u16* kg1 = kg0 + (size_t)32 * DK;
  const u16* vg0 = vb + (size_t)srow * S_LEN + sc8;
  const u16* vg1 = vg0 + (size_t)32 * S_LEN;
  u16* Kl0 = Ks + srow * ASTR + sc8;
  u16* Kl1 = Kl0 + 32 * ASTR;
  u16* Vl0 = Vts + srow * ASTR + sc8;
  u16* Vl1 = Vl0 + 32 * ASTR;
  u16* Pw = Ps[w];

  // prefetch tile kt=0
  uint4 kr0 = *(const uint4*)kg0, kr1 = *(const uint4*)kg1;
  uint4 vr0 = *(const uint4*)vg0, vr1 = *(const uint4*)vg1;
  float br = (t < 192) ? btp[t] : 0.f;

  for (int kt = 0; kt < S_LEN; kt += 64) {
    const int D = kt - q0;
    const bool far = (D >= 256) || (D <= -192);   // bucket saturated across whole (128q,64k) tile
    *(uint4*)Kl0 = kr0; *(uint4*)Kl1 = kr1;
    *(uint4*)Vl0 = vr0; *(uint4*)Vl1 = vr1;
    if (t < 192) band[t] = br;
    __syncthreads();
    if (kt + 64 < S_LEN) {
      kr0 = *(const uint4*)(kg0 + (size_t)(kt + 64) * DK);
      kr1 = *(const uint4*)(kg1 + (size_t)(kt + 64) * DK);
      vr0 = *(const uint4*)(vg0 + (kt + 64));
      vr1 = *(const uint4*)(vg1 + (kt + 64));
      br = (t < 192) ? btp[kt + 64 + t] : 0.f;
    }

    // ---- K fragments once into regs (A operand), shared by both q-groups ----
    bf16x8_t kf[2][4];
    #pragma unroll
    for (int kc = 0; kc < 2; ++kc)
      #pragma unroll
      for (int nt = 0; nt < 4; ++nt)
        kf[kc][nt] = *(const bf16x8_t*)(Ks + (nt * 16 + c) * ASTR + kc * 32 + quad * 8);

    // ---- S^T = K·Q^T: s4t[qg][nt][r] = S[q = c][k = nt*16 + quad*4 + r] ----
    f32x4_t s4t[2][4] = {};
    #pragma unroll
    for (int qg = 0; qg < 2; ++qg)
      #pragma unroll
      for (int kc = 0; kc < 2; ++kc)
        #pragma unroll
        for (int nt = 0; nt < 4; ++nt)
          s4t[qg][nt] = __builtin_amdgcn_mfma_f32_16x16x32_bf16(kf[kc][nt], qfrag[qg][kc], s4t[qg][nt], 0, 0, 0);

    // ---- V B-frags once into regs (kf dead), shared by both q-groups ----
    bf16x8_t vf[2][4];
    #pragma unroll
    for (int kc = 0; kc < 2; ++kc)
      #pragma unroll
      for (int nt = 0; nt < 4; ++nt)
        vf[kc][nt] = *(const bf16x8_t*)(Vts + (nt * 16 + c) * ASTR + kc * 32 + quad * 8);

    const float bfc = band[127];   // far-tile wave-uniform bias (delta = D)
    #pragma unroll
    for (int qg = 0; qg < 2; ++qg) {
      // p = exp2(s*log2e + b'); l row-sum is scalar (lane's q = c); P packed row-contiguous
      const int bnd0 = 127 + quad * 4 - (w * 32 + qg * 16) - c;   // + nt*16 + r
      #pragma unroll
      for (int nt = 0; nt < 4; ++nt) {
        float p0, p1, p2, p3;
        if (far) {
          p0 = fexp2(fmaf(s4t[qg][nt][0], LOG2E, bfc));
          p1 = fexp2(fmaf(s4t[qg][nt][1], LOG2E, bfc));
          p2 = fexp2(fmaf(s4t[qg][nt][2], LOG2E, bfc));
          p3 = fexp2(fmaf(s4t[qg][nt][3], LOG2E, bfc));
        } else {
          const int bi = bnd0 + nt * 16;
          p0 = fexp2(fmaf(s4t[qg][nt][0], LOG2E, band[bi]));
          p1 = fexp2(fmaf(s4t[qg][nt][1], LOG2E, band[bi + 1]));
          p2 = fexp2(fmaf(s4t[qg][nt][2], LOG2E, band[bi + 2]));
          p3 = fexp2(fmaf(s4t[qg][nt][3], LOG2E, band[bi + 3]));
        }
        lp[qg] += (p0 + p1) + (p2 + p3);
        union { float f; u32 u; } c0, c1, c2, c3;
        c0.f = p0; c1.f = p1; c2.f = p2; c3.f = p3;
        uint2 pk;
        pk.x = ((c0.u + 0x8000u) >> 16) | ((c1.u + 0x8000u) & 0xffff0000u);
        pk.y = ((c2.u + 0x8000u) >> 16) | ((c3.u + 0x8000u) & 0xffff0000u);
        *(uint2*)(Pw + c * ASTR + nt * 16 + quad * 4) = pk;   // P[q=c][k=nt*16+quad*4 ..+3]
      }
      // O += P V (wave-synchronous P round-trip; WAR on Pw between q-groups same-wave ordered)
      #pragma unroll
      for (int kc = 0; kc < 2; ++kc) {
        bf16x8_t afr = *(const bf16x8_t*)(Pw + c * ASTR + kc * 32 + quad * 8);
        #pragma unroll
        for (int nt = 0; nt < 4; ++nt)
          O[qg][nt] = __builtin_amdgcn_mfma_f32_16x16x32_bf16(afr, vf[kc][nt], O[qg][nt], 0, 0, 0);
      }
    }
    __syncthreads();   // all reads done before next tile's staging writes
  }

  // ---- l: reduce over quads (each quad covered distinct k), transpose via per-wave LDS ----
  #pragma unroll
  for (int qg = 0; qg < 2; ++qg) {
    lp[qg] += __shfl_xor(lp[qg], 16, 64);
    lp[qg] += __shfl_xor(lp[qg], 32, 64);
  }
  if (quad == 0) { l_lds[w][c] = lp[0]; l_lds[w][16 + c] = lp[1]; }
  // wave-synchronous read-back (same wave wrote it; lgkmcnt ordering)
  #pragma unroll
  for (int qg = 0; qg < 2; ++qg)
    #pragma unroll
    for (int r = 0; r < 4; ++r) {
      float inv = 1.0f / l_lds[w][qg * 16 + quad * 4 + r];
      int s = q0 + w * 32 + qg * 16 + quad * 4 + r;
      u16* cp = ctx + ((size_t)(b * S_LEN + s)) * DMODEL + h * DK + c;
      #pragma unroll
      for (int nt = 0; nt < 4; ++nt)
        cp[nt * 16] = f2b(O[qg][nt][r] * inv);
    }
}

extern "C" void kernel_launch(void* const* d_in, const int* in_sizes, int n_in,
                              void* d_out, int out_size, void* d_ws, size_t ws_size,
                              hipStream_t stream) {
  const float* x   = (const float*)d_in[0];
  const float* Wq  = (const float*)d_in[1];
  const float* Wk  = (const float*)d_in[2];
  const float* Wv  = (const float*)d_in[3];
  const float* Wo  = (const float*)d_in[4];
  const float* rel = (const float*)d_in[5];
  float* out = (float*)d_out;

  char* ws = (char*)d_ws;
  size_t off = 0;
  auto carve = [&](size_t bytes) -> char* {
    char* p = ws + off;
    off += (bytes + 255) & ~(size_t)255;
    return p;
  };
  u16*   xb   = (u16*)  carve((size_t)MROWS * DMODEL * 2);       // x bf16
  u16*   Wall = (u16*)  carve((size_t)3 * DMODEL * DMODEL * 2);  // [Wq^T;Wk^T;Wv^T] bf16 [3072][1024]
  u16*   Wto  = (u16*)  carve((size_t)DMODEL * DMODEL * 2);
  u16*   qb16 = (u16*)  carve((size_t)4194304 * 2);              // [bh][s][64] bf16
  u16*   kb16 = (u16*)  carve((size_t)4194304 * 2);
  u16*   vt16 = (u16*)  carve((size_t)4194304 * 2);              // [bh][64][s] bf16
  float* btab = (float*)carve(((size_t)NH * 4095 + 256) * 4);    // +tail slack (band stage)
  u16*   ctxb = (u16*)  carve((size_t)4194304 * 2);              // [b][s][1024] bf16

  prep_kernel<<<8448, 256, 0, stream>>>(x, Wq, Wk, Wv, Wo, rel, xb, Wall, Wto, btab);

  dim3 qkvgrid(32, 24);  // M/128, 3072/128
  gemm128_kernel<<<qkvgrid, 256, 0, stream>>>(xb, Wall, nullptr, qb16, kb16, vt16, 1);

  dim3 agrid(S_LEN / 128, 32);  // 128-q tiles, B*H
  attn_mfma_kernel<<<agrid, 256, 0, stream>>>(qb16, kb16, vt16, btab, ctxb);

  dim3 ogrid(32, 8);
  gemm128_kernel<<<ogrid, 256, 0, stream>>>(ctxb, Wto, out, nullptr, nullptr, nullptr, 0);
}

// Round 11
// 197.127 us; speedup vs baseline: 1.0858x; 1.0858x over previous
//
#include <hip/hip_runtime.h>
#include <math.h>

typedef unsigned short u16;
typedef unsigned int u32;
typedef __attribute__((ext_vector_type(8))) short bf16x8_t;
typedef __attribute__((ext_vector_type(4))) float f32x4_t;

#define S_LEN  2048
#define NH     16
#define DK     64
#define DMODEL 1024
#define MROWS  4096   // B*S
#define LOG2E  1.44269504088896f

__device__ inline u16 f2b(float f) {
  union { float f; u32 u; } c; c.f = f;
  u32 u = c.u;
  return (u16)((u + 0x7fffu + ((u >> 16) & 1u)) >> 16);  // RNE bf16
}

__device__ __forceinline__ float fexp2(float x) {
#if __has_builtin(__builtin_amdgcn_exp2f)
  return __builtin_amdgcn_exp2f(x);
#else
  return exp2f(x);
#endif
}

// ---------------- global -> LDS DMA: wave-uniform LDS base, lane deposits 16B at base + lane*16 ----------------
// (correctness HW-validated in R6: passed absmax 0.0117 with this exact incantation)
__device__ __forceinline__ void stage16(const u16* gp_lane, u16* lds_base) {
#if __has_builtin(__builtin_amdgcn_global_load_lds)
  __builtin_amdgcn_global_load_lds((const __attribute__((address_space(1))) u32*)gp_lane,
                                   (__attribute__((address_space(3))) u32*)lds_base, 16, 0, 0);
#else
  *(uint4*)(lds_base + (threadIdx.x & 63) * 8) = *(const uint4*)gp_lane;
#endif
}

// ---------------- fused prep: cast x, transpose+cast 4 weights, bias table ----------------
__global__ void prep_kernel(const float* __restrict__ x,
                            const float* __restrict__ Wq, const float* __restrict__ Wk,
                            const float* __restrict__ Wv, const float* __restrict__ Wo,
                            const float* __restrict__ rel,
                            u16* __restrict__ xb, u16* __restrict__ Wall,
                            u16* __restrict__ Wto, float* __restrict__ btab) {
  __shared__ float tile[32][33];
  const int bid = blockIdx.x, t = threadIdx.x;
  if (bid < 4096) {
    int i = (bid * 256 + t) * 4;
    float4 v = *(const float4*)(x + i);
    ushort4 o;
    o.x = f2b(v.x); o.y = f2b(v.y); o.z = f2b(v.z); o.w = f2b(v.w);
    *(ushort4*)(xb + i) = o;
  } else if (bid < 8192) {
    int bid2 = bid - 4096;
    int z = bid2 >> 10, rem = bid2 & 1023;
    const float* W; u16* Wt;
    switch (z) {
      case 0: W = Wq; Wt = Wall; break;
      case 1: W = Wk; Wt = Wall + (size_t)DMODEL * DMODEL; break;
      case 2: W = Wv; Wt = Wall + (size_t)2 * DMODEL * DMODEL; break;
      default: W = Wo; Wt = Wto; break;
    }
    int bc = (rem & 31) * 32, br = (rem >> 5) * 32;
    int tx = t & 31, ty = t >> 5;
    #pragma unroll
    for (int yy = 0; yy < 32; yy += 8)
      tile[ty + yy][tx] = W[(size_t)(br + ty + yy) * DMODEL + bc + tx];
    __syncthreads();
    #pragma unroll
    for (int yy = 0; yy < 32; yy += 8)
      Wt[(size_t)(bc + ty + yy) * DMODEL + br + tx] = f2b(tile[tx][ty + yy]);
  } else {
    // bias table: btab[h][delta+2047] = (bias(h,delta) - 16) * log2(e)   [exp2-domain]
    int idx = (bid - 8192) * 256 + t;
    if (idx < NH * 4095) {
      int h = idx / 4095;
      int dpos = idx - h * 4095;
      int delta = dpos - 2047;               // j - i; reference n = i - j
      int ret = (delta > 0) ? 16 : 0;
      int n = delta < 0 ? -delta : delta;
      int bucket;
      if (n < 8) {
        bucket = ret + n;
      } else {
        float vf = logf((float)n * 0.125f) / 2.7725887222397811f * 8.0f;
        int vil = 8 + (int)vf;
        bucket = ret + (vil < 15 ? vil : 15);
      }
      btab[idx] = (rel[bucket * NH + h] - 16.0f) * LOG2E;
    }
  }
}

// ---------------- 128x128 bf16 MFMA GEMM ----------------
// MODE 0: out-projection, C fp32 [4096][1024]; manual staging + register prefetch (R5-proven;
//         grid is only 256 blocks = 1/CU, so DMA's barrier vmcnt(0) drain would be exposed).
// MODE 1: fused QKV, Bt=[3072][1024]; m97-style global_load_lds DMA staging, unpadded [128][32]
//         (768 blocks = 3/CU co-resident hides the drain; m97 measured 517->874 TF for this swap).
#define GSTR 56   // manual-path LDS row stride (112 B): 16B-aligned, 2-way bank aliasing (free)
template <int MODE>
__global__ __launch_bounds__(256) void gemm128_kernel(const u16* __restrict__ A,
                                                      const u16* __restrict__ Bt,
                                                      float* __restrict__ C,
                                                      u16* __restrict__ q16,
                                                      u16* __restrict__ k16,
                                                      u16* __restrict__ vt16) {
  // MODE 1: staging needs 128*32=4096 u16; q/k transpose epilogue needs 64*72=4608 u16.
  constexpr int ABSZ = (MODE == 1) ? 4608 : 128 * GSTR;
  constexpr int FSTR = (MODE == 1) ? 32 : GSTR;
  __shared__ __align__(16) u16 As[ABSZ];
  __shared__ __align__(16) u16 Bs[ABSZ];
  const int t = threadIdx.x, w = t >> 6, l = t & 63;
  const int c = l & 15, quad = l >> 4;
  const int m0 = blockIdx.x * 128, n0 = blockIdx.y * 128;
  const int wm = (w & 1) * 64, wn = (w >> 1) * 64;

  f32x4_t acc[16] = {};

  if constexpr (MODE == 1) {
    // DMA map: wave w stages rows w*32..+31 (two 16-row slabs); lane l -> row l>>2, chunk l&3
    const int sr = l >> 2;
    const int k8 = (l & 3) * 8;
    const u16* Ag0 = A  + (size_t)(m0 + w * 32 + sr) * DMODEL + k8;
    const u16* Ag1 = Ag0 + (size_t)16 * DMODEL;
    const u16* Bg0 = Bt + (size_t)(n0 + w * 32 + sr) * DMODEL + k8;
    const u16* Bg1 = Bg0 + (size_t)16 * DMODEL;
    u16* Al = As + w * 1024;   // w*32 rows * 32 cols
    u16* Bl = Bs + w * 1024;
    for (int k0 = 0; k0 < DMODEL; k0 += 32) {
      __syncthreads();   // prior frag reads done
      stage16(Ag0 + k0, Al);
      stage16(Ag1 + k0, Al + 512);
      stage16(Bg0 + k0, Bl);
      stage16(Bg1 + k0, Bl + 512);
      __syncthreads();   // vmcnt drain before barrier completes staging
      bf16x8_t af[4], bfr[4];
      #pragma unroll
      for (int i = 0; i < 4; ++i) {
        af[i]  = *(const bf16x8_t*)(As + (wm + i * 16 + c) * FSTR + quad * 8);
        bfr[i] = *(const bf16x8_t*)(Bs + (wn + i * 16 + c) * FSTR + quad * 8);
      }
      #pragma unroll
      for (int mt = 0; mt < 4; ++mt)
        #pragma unroll
        for (int nt = 0; nt < 4; ++nt)
          acc[mt * 4 + nt] = __builtin_amdgcn_mfma_f32_16x16x32_bf16(af[mt], bfr[nt], acc[mt * 4 + nt], 0, 0, 0);
    }
  } else {
    // manual staging + register prefetch (full 128x32 coverage per matrix)
    const int sr = t >> 2;
    const int k8 = (t & 3) * 8;
    const u16* Ag0 = A  + (size_t)(m0 + sr) * DMODEL + k8;
    const u16* Ag1 = Ag0 + (size_t)64 * DMODEL;
    const u16* Bg0 = Bt + (size_t)(n0 + sr) * DMODEL + k8;
    const u16* Bg1 = Bg0 + (size_t)64 * DMODEL;
    u16* Al0 = As + sr * GSTR + k8;
    u16* Al1 = Al0 + 64 * GSTR;
    u16* Bl0 = Bs + sr * GSTR + k8;
    u16* Bl1 = Bl0 + 64 * GSTR;

    uint4 a0 = *(const uint4*)Ag0, a1 = *(const uint4*)Ag1;
    uint4 b0 = *(const uint4*)Bg0, b1 = *(const uint4*)Bg1;
    for (int k0 = 0; k0 < DMODEL; k0 += 32) {
      __syncthreads();
      *(uint4*)Al0 = a0; *(uint4*)Al1 = a1;
      *(uint4*)Bl0 = b0; *(uint4*)Bl1 = b1;
      __syncthreads();
      if (k0 + 32 < DMODEL) {
        a0 = *(const uint4*)(Ag0 + k0 + 32);
        a1 = *(const uint4*)(Ag1 + k0 + 32);
        b0 = *(const uint4*)(Bg0 + k0 + 32);
        b1 = *(const uint4*)(Bg1 + k0 + 32);
      }
      bf16x8_t af[4], bfr[4];
      #pragma unroll
      for (int i = 0; i < 4; ++i) {
        af[i]  = *(const bf16x8_t*)(As + (wm + i * 16 + c) * FSTR + quad * 8);
        bfr[i] = *(const bf16x8_t*)(Bs + (wn + i * 16 + c) * FSTR + quad * 8);
      }
      #pragma unroll
      for (int mt = 0; mt < 4; ++mt)
        #pragma unroll
        for (int nt = 0; nt < 4; ++nt)
          acc[mt * 4 + nt] = __builtin_amdgcn_mfma_f32_16x16x32_bf16(af[mt], bfr[nt], acc[mt * 4 + nt], 0, 0, 0);
    }
  }

  // ---- epilogue; C/D layout: col = lane&15, row = quad*4 + reg ----
  if constexpr (MODE == 0) {
    #pragma unroll
    for (int mt = 0; mt < 4; ++mt) {
      int grow0 = m0 + wm + mt * 16 + quad * 4;
      #pragma unroll
      for (int nt = 0; nt < 4; ++nt) {
        int gcol = n0 + wn + nt * 16 + c;
        #pragma unroll
        for (int r = 0; r < 4; ++r)
          C[(size_t)(grow0 + r) * DMODEL + gcol] = acc[mt * 4 + nt][r];
      }
    }
  } else {
    const int whichblk = n0 >> 10;   // uniform across block
    if (whichblk == 2) {
      // vt [bh][dk][s]: contiguous along s (= acc rows) -> direct ushort4
      #pragma unroll
      for (int mt = 0; mt < 4; ++mt) {
        int grow0 = m0 + wm + mt * 16 + quad * 4;
        int b = grow0 >> 11, s0 = grow0 & 2047;
        #pragma unroll
        for (int nt = 0; nt < 4; ++nt) {
          int cc = (n0 + wn + nt * 16 + c) & 1023;
          int hh = cc >> 6, dk = cc & 63;
          f32x4_t v4 = acc[mt * 4 + nt];
          ushort4 o;
          o.x = f2b(v4[0]); o.y = f2b(v4[1]); o.z = f2b(v4[2]); o.w = f2b(v4[3]);
          *(ushort4*)(vt16 + (((size_t)(b * NH + hh)) * DK + dk) * S_LEN + s0) = o;
        }
      }
    } else {
      // q/k [bh][s][dk]: per-wave LDS transpose (64x64 tile, stride 72), 2 rounds over As/Bs
      u16* tb = (w & 1) ? Bs : As;
      const int base_mw = m0 + wm;
      const int bb = base_mw >> 11, s0g = base_mw & 2047;
      const int cc = (n0 + wn) & 1023;
      const int hh = cc >> 6;
      u16* qk = (whichblk == 0 ? q16 : k16) + (((size_t)(bb * NH + hh)) * S_LEN + s0g) * DK;
      __syncthreads();   // all frag reads of As/Bs complete
      #pragma unroll
      for (int round = 0; round < 2; ++round) {
        if ((w >> 1) == round) {
          #pragma unroll
          for (int mt = 0; mt < 4; ++mt)
            #pragma unroll
            for (int nt = 0; nt < 4; ++nt)
              #pragma unroll
              for (int r = 0; r < 4; ++r)
                tb[(mt * 16 + quad * 4 + r) * 72 + nt * 16 + c] = f2b(acc[mt * 4 + nt][r]);
          #pragma unroll
          for (int i = 0; i < 8; ++i) {
            int lrow = i * 8 + (l >> 3);
            int chk = l & 7;
            uint4 vv = *(const uint4*)(tb + lrow * 72 + chk * 8);
            *(uint4*)(qk + (size_t)lrow * DK + chk * 8) = vv;
          }
        }
        __syncthreads();
      }
    }
  }
}

// ---------------- MFMA flash attention (R9-proven): 32 q/wave, reg-shared K/V frags ----------------
// q,k: bf16 [bh][s][64]; vt: bf16 [bh][64][s]; ctx out: bf16 [b][s][1024]
#define ASTR 72   // u16 row stride (144 B): 16B-aligned, 2-way-max bank aliasing
__global__ __launch_bounds__(256) void attn_mfma_kernel(const u16* __restrict__ q,
                                                        const u16* __restrict__ k,
                                                        const u16* __restrict__ vt,
                                                        const float* __restrict__ btab,
                                                        u16* __restrict__ ctx) {
  __shared__ __align__(16) u16 Ks[64 * ASTR];
  __shared__ __align__(16) u16 Vts[64 * ASTR];
  __shared__ __align__(16) u16 Ps[4][16 * ASTR];  // per-wave 16-row P buffer (reused per q-group)
  __shared__ float band[192];                     // exp2-domain bias band

  const int t = threadIdx.x;
  const int w = t >> 6, l = t & 63;
  const int c = l & 15, quad = l >> 4;
  const int bh = blockIdx.y;
  const int h = bh & (NH - 1), b = bh >> 4;
  const int q0 = blockIdx.x * 128;

  const u16* qb = q + (size_t)bh * S_LEN * DK;
  const u16* kb = k + (size_t)bh * S_LEN * DK;
  const u16* vb = vt + (size_t)bh * DK * S_LEN;
  const float* btp = btab + h * 4095 + (2047 - 127 - q0);

  bf16x8_t qfrag[2][2];
  #pragma unroll
  for (int qg = 0; qg < 2; ++qg) {
    const u16* qp = qb + (size_t)(q0 + w * 32 + qg * 16 + c) * DK + quad * 8;
    qfrag[qg][0] = *(const bf16x8_t*)(qp);
    qfrag[qg][1] = *(const bf16x8_t*)(qp + 32);
  }

  float lp[2][4] = {};
  f32x4_t O[2][4] = {};

  const int srow = t >> 3;
  const int sc8 = (t & 7) * 8;
  const u16* kg0 = kb + (size_t)srow * DK + sc8;
  const u16* kg1 = kg0 + (size_t)32 * DK;
  const u16* vg0 = vb + (size_t)srow * S_LEN + sc8;
  const u16* vg1 = vg0 + (size_t)32 * S_LEN;
  u16* Kl0 = Ks + srow * ASTR + sc8;
  u16* Kl1 = Kl0 + 32 * ASTR;
  u16* Vl0 = Vts + srow * ASTR + sc8;
  u16* Vl1 = Vl0 + 32 * ASTR;
  u16* Pw = Ps[w];

  uint4 kr0 = *(const uint4*)kg0, kr1 = *(const uint4*)kg1;
  uint4 vr0 = *(const uint4*)vg0, vr1 = *(const uint4*)vg1;
  float br = (t < 192) ? btp[t] : 0.f;

  for (int kt = 0; kt < S_LEN; kt += 64) {
    const int D = kt - q0;
    const bool far = (D >= 256) || (D <= -192);
    *(uint4*)Kl0 = kr0; *(uint4*)Kl1 = kr1;
    *(uint4*)Vl0 = vr0; *(uint4*)Vl1 = vr1;
    if (t < 192) band[t] = br;
    __syncthreads();
    if (kt + 64 < S_LEN) {
      kr0 = *(const uint4*)(kg0 + (size_t)(kt + 64) * DK);
      kr1 = *(const uint4*)(kg1 + (size_t)(kt + 64) * DK);
      vr0 = *(const uint4*)(vg0 + (kt + 64));
      vr1 = *(const uint4*)(vg1 + (kt + 64));
      br = (t < 192) ? btp[kt + 64 + t] : 0.f;
    }

    bf16x8_t kf[2][4];
    #pragma unroll
    for (int kc = 0; kc < 2; ++kc)
      #pragma unroll
      for (int nt = 0; nt < 4; ++nt)
        kf[kc][nt] = *(const bf16x8_t*)(Ks + (nt * 16 + c) * ASTR + kc * 32 + quad * 8);

    f32x4_t s4[2][4] = {};
    #pragma unroll
    for (int qg = 0; qg < 2; ++qg)
      #pragma unroll
      for (int kc = 0; kc < 2; ++kc)
        #pragma unroll
        for (int nt = 0; nt < 4; ++nt)
          s4[qg][nt] = __builtin_amdgcn_mfma_f32_16x16x32_bf16(qfrag[qg][kc], kf[kc][nt], s4[qg][nt], 0, 0, 0);

    bf16x8_t vf[2][4];
    #pragma unroll
    for (int kc = 0; kc < 2; ++kc)
      #pragma unroll
      for (int nt = 0; nt < 4; ++nt)
        vf[kc][nt] = *(const bf16x8_t*)(Vts + (nt * 16 + c) * ASTR + kc * 32 + quad * 8);

    const float bfc = band[127];
    #pragma unroll
    for (int qg = 0; qg < 2; ++qg) {
      const int bnd0 = c - (w * 32 + qg * 16 + quad * 4) + 127;
      if (far) {
        #pragma unroll
        for (int nt = 0; nt < 4; ++nt)
          #pragma unroll
          for (int r = 0; r < 4; ++r) {
            float p = fexp2(fmaf(s4[qg][nt][r], LOG2E, bfc));
            lp[qg][r] += p;
            union { float f; u32 u; } cv; cv.f = p;
            Pw[(quad * 4 + r) * ASTR + nt * 16 + c] = (u16)((cv.u + 0x8000u) >> 16);
          }
      } else {
        #pragma unroll
        for (int nt = 0; nt < 4; ++nt)
          #pragma unroll
          for (int r = 0; r < 4; ++r) {
            float p = fexp2(fmaf(s4[qg][nt][r], LOG2E, band[bnd0 + nt * 16 - r]));
            lp[qg][r] += p;
            union { float f; u32 u; } cv; cv.f = p;
            Pw[(quad * 4 + r) * ASTR + nt * 16 + c] = (u16)((cv.u + 0x8000u) >> 16);
          }
      }
      #pragma unroll
      for (int kc = 0; kc < 2; ++kc) {
        bf16x8_t afr = *(const bf16x8_t*)(Pw + c * ASTR + kc * 32 + quad * 8);
        #pragma unroll
        for (int nt = 0; nt < 4; ++nt)
          O[qg][nt] = __builtin_amdgcn_mfma_f32_16x16x32_bf16(afr, vf[kc][nt], O[qg][nt], 0, 0, 0);
      }
    }
    __syncthreads();
  }

  #pragma unroll
  for (int off = 1; off < 16; off <<= 1)
    #pragma unroll
    for (int qg = 0; qg < 2; ++qg)
      #pragma unroll
      for (int r = 0; r < 4; ++r)
        lp[qg][r] += __shfl_xor(lp[qg][r], off, 64);
  #pragma unroll
  for (int qg = 0; qg < 2; ++qg)
    #pragma unroll
    for (int r = 0; r < 4; ++r) {
      float inv = 1.0f / lp[qg][r];
      int s = q0 + w * 32 + qg * 16 + quad * 4 + r;
      u16* cp = ctx + ((size_t)(b * S_LEN + s)) * DMODEL + h * DK + c;
      #pragma unroll
      for (int nt = 0; nt < 4; ++nt)
        cp[nt * 16] = f2b(O[qg][nt][r] * inv);
    }
}

extern "C" void kernel_launch(void* const* d_in, const int* in_sizes, int n_in,
                              void* d_out, int out_size, void* d_ws, size_t ws_size,
                              hipStream_t stream) {
  const float* x   = (const float*)d_in[0];
  const float* Wq  = (const float*)d_in[1];
  const float* Wk  = (const float*)d_in[2];
  const float* Wv  = (const float*)d_in[3];
  const float* Wo  = (const float*)d_in[4];
  const float* rel = (const float*)d_in[5];
  float* out = (float*)d_out;

  char* ws = (char*)d_ws;
  size_t off = 0;
  auto carve = [&](size_t bytes) -> char* {
    char* p = ws + off;
    off += (bytes + 255) & ~(size_t)255;
    return p;
  };
  u16*   xb   = (u16*)  carve((size_t)MROWS * DMODEL * 2);       // x bf16
  u16*   Wall = (u16*)  carve((size_t)3 * DMODEL * DMODEL * 2);  // [Wq^T;Wk^T;Wv^T] bf16 [3072][1024]
  u16*   Wto  = (u16*)  carve((size_t)DMODEL * DMODEL * 2);
  u16*   qb16 = (u16*)  carve((size_t)4194304 * 2);              // [bh][s][64] bf16
  u16*   kb16 = (u16*)  carve((size_t)4194304 * 2);
  u16*   vt16 = (u16*)  carve((size_t)4194304 * 2);              // [bh][64][s] bf16
  float* btab = (float*)carve(((size_t)NH * 4095 + 256) * 4);    // +tail slack (band stage)
  u16*   ctxb = (u16*)  carve((size_t)4194304 * 2);              // [b][s][1024] bf16

  prep_kernel<<<8448, 256, 0, stream>>>(x, Wq, Wk, Wv, Wo, rel, xb, Wall, Wto, btab);

  dim3 qkvgrid(32, 24);  // M/128, 3072/128
  gemm128_kernel<1><<<qkvgrid, 256, 0, stream>>>(xb, Wall, nullptr, qb16, kb16, vt16);

  dim3 agrid(S_LEN / 128, 32);  // 128-q tiles, B*H
  attn_mfma_kernel<<<agrid, 256, 0, stream>>>(qb16, kb16, vt16, btab, ctxb);

  dim3 ogrid(32, 8);
  gemm128_kernel<0><<<ogrid, 256, 0, stream>>>(ctxb, Wto, out, nullptr, nullptr, nullptr);
}